// Round 4
// baseline (67.749 us; speedup 1.0000x reference)
//
#include <hip/hip_runtime.h>
#include <math.h>

#define NB 4
#define NV 5023
#define NF 9976
#define NH 512
#define NW 512
#define NU 256   // albedo resolution

// CONST_FACTOR
__device__ __constant__ float d_cf[9] = {
    0.28209479177387814f,
    1.0233267079464885f,
    1.0233267079464885f,
    1.0233267079464885f,
    0.8580855308091875f,
    0.8580855308091875f,
    0.8580855308091875f,
    0.42904276540459376f,
    0.24770795610037571f
};

#define NRM_FLOATS (NB * NV * 3)   // 60276

// ---------------------------------------------------------------------------
// Kernel 0: zero the normal accumulator (runtime fillBuffer is ~43us for
// tiny buffers inside a captured graph; this takes ~2us).
// ---------------------------------------------------------------------------
__global__ void zero_nrm_kernel(float* __restrict__ nrm) {
    int i = blockIdx.x * blockDim.x + threadIdx.x;
    if (i < NRM_FLOATS) nrm[i] = 0.0f;
}

// ---------------------------------------------------------------------------
// Kernel 1: accumulate (unnormalized) vertex normals via atomics.
// ---------------------------------------------------------------------------
__global__ void face_accum_kernel(const float* __restrict__ verts,
                                  const int*   __restrict__ faces,
                                  float*       __restrict__ nrm) {
    int idx = blockIdx.x * blockDim.x + threadIdx.x;   // b*NF + f
    if (idx >= NB * NF) return;
    int b = idx / NF;
    int f = idx - b * NF;

    int i0 = faces[f * 3 + 0];
    int i1 = faces[f * 3 + 1];
    int i2 = faces[f * 3 + 2];

    const float* vb = verts + (size_t)b * NV * 3;
    float v0x = vb[i0 * 3 + 0], v0y = vb[i0 * 3 + 1], v0z = vb[i0 * 3 + 2];
    float v1x = vb[i1 * 3 + 0], v1y = vb[i1 * 3 + 1], v1z = vb[i1 * 3 + 2];
    float v2x = vb[i2 * 3 + 0], v2y = vb[i2 * 3 + 1], v2z = vb[i2 * 3 + 2];

    float ax = v1x - v0x, ay = v1y - v0y, az = v1z - v0z;
    float bx = v2x - v0x, by = v2y - v0y, bz = v2z - v0z;
    float cx = ay * bz - az * by;
    float cy = az * bx - ax * bz;
    float cz = ax * by - ay * bx;

    float* nb = nrm + (size_t)b * NV * 3;
    atomicAdd(&nb[i0 * 3 + 0], cx);
    atomicAdd(&nb[i0 * 3 + 1], cy);
    atomicAdd(&nb[i0 * 3 + 2], cz);
    atomicAdd(&nb[i1 * 3 + 0], cx);
    atomicAdd(&nb[i1 * 3 + 1], cy);
    atomicAdd(&nb[i1 * 3 + 2], cz);
    atomicAdd(&nb[i2 * 3 + 0], cx);
    atomicAdd(&nb[i2 * 3 + 1], cy);
    atomicAdd(&nb[i2 * 3 + 2], cz);
}

// ---------------------------------------------------------------------------
// Kernel 2 (fused prep):
//  part A: per (b,f) pack a 64B face record:
//    [u0,v0,u1,v1, u2,v2,n0x,n0y, n0z,n1x,n1y,n1z, n2x,n2y,n2z,pad]
//  part B: interleave albedos (B,3,U,U) -> (B,U,U,4) float4
// ---------------------------------------------------------------------------
#define FACE_ITEMS   (NB * NF)
#define FACE_BLOCKS  ((FACE_ITEMS + 255) / 256)
#define ALB_ITEMS    (NB * NU * NU)
#define ALB_BLOCKS   ((ALB_ITEMS + 255) / 256)

__global__ void prep_kernel(const float* __restrict__ nrm,
                            const int*   __restrict__ faces,
                            const float* __restrict__ uvc,      // (1,F,3,3)
                            const float* __restrict__ albedos,  // (B,3,U,U)
                            float*       __restrict__ recs,     // (B*F,16)
                            float4*      __restrict__ aint) {   // (B*U*U)
    if (blockIdx.x < FACE_BLOCKS) {
        int idx = blockIdx.x * blockDim.x + threadIdx.x;       // b*NF + f
        if (idx >= FACE_ITEMS) return;
        int b = idx / NF;
        int f = idx - b * NF;

        int i0 = faces[f * 3 + 0];
        int i1 = faces[f * 3 + 1];
        int i2 = faces[f * 3 + 2];

        const float* nb = nrm + (size_t)b * NV * 3;
        float n0x = nb[i0 * 3 + 0], n0y = nb[i0 * 3 + 1], n0z = nb[i0 * 3 + 2];
        float n1x = nb[i1 * 3 + 0], n1y = nb[i1 * 3 + 1], n1z = nb[i1 * 3 + 2];
        float n2x = nb[i2 * 3 + 0], n2y = nb[i2 * 3 + 1], n2z = nb[i2 * 3 + 2];

        float l0 = 1.0f / fmaxf(sqrtf(n0x*n0x + n0y*n0y + n0z*n0z), 1e-6f);
        float l1 = 1.0f / fmaxf(sqrtf(n1x*n1x + n1y*n1y + n1z*n1z), 1e-6f);
        float l2 = 1.0f / fmaxf(sqrtf(n2x*n2x + n2y*n2y + n2z*n2z), 1e-6f);

        const float* uvf = uvc + (size_t)f * 9;  // [vert][comp]

        float4* r = (float4*)(recs + (size_t)idx * 16);
        r[0] = make_float4(uvf[0], uvf[1], uvf[3], uvf[4]);          // u0 v0 u1 v1
        r[1] = make_float4(uvf[6], uvf[7], n0x * l0, n0y * l0);      // u2 v2 n0x n0y
        r[2] = make_float4(n0z * l0, n1x * l1, n1y * l1, n1z * l1);  // n0z n1
        r[3] = make_float4(n2x * l2, n2y * l2, n2z * l2, 0.0f);      // n2 pad
    } else {
        int j = (blockIdx.x - FACE_BLOCKS) * blockDim.x + threadIdx.x;  // b*U*U + y*U + x
        if (j >= ALB_ITEMS) return;
        int b = j / (NU * NU);
        int o = j - b * (NU * NU);
        const float* ab = albedos + (size_t)b * 3 * NU * NU;
        aint[j] = make_float4(ab[o], ab[NU * NU + o], ab[2 * NU * NU + o], 0.0f);
    }
}

// ---------------------------------------------------------------------------
// Kernel 3: per-pixel render using packed face records + interleaved albedo.
// ---------------------------------------------------------------------------
__global__ void render_kernel(const float4* __restrict__ recs,   // (B*F,4 float4)
                              const float4* __restrict__ aint,   // (B,U,U)
                              const float* __restrict__ lights,
                              const float* __restrict__ bary,    // (B,H,W,1,3)
                              const int*   __restrict__ p2f,     // (B,H,W,1)
                              float*       __restrict__ out) {   // (B,3,H,W)
    const int b = blockIdx.y;
    const int p = blockIdx.x * blockDim.x + threadIdx.x;   // h*W + w

    __shared__ float Ls[27];
    if (threadIdx.x < 27) {
        int k = threadIdx.x / 3;
        int c = threadIdx.x - k * 3;
        Ls[threadIdx.x] = lights[(b * 9 + k) * 3 + c] * d_cf[k];
    }
    __syncthreads();
    if (p >= NH * NW) return;

    const int pix = b * NH * NW + p;
    const int f = p2f[pix];

    float u = 0.f, v = 0.f, nx = 0.f, ny = 0.f, nz = 0.f;
    if (f >= 0) {
        const float* bc = bary + (size_t)pix * 3;
        float b0 = bc[0], b1 = bc[1], b2 = bc[2];

        const float4* r = recs + ((size_t)b * NF + f) * 4;
        float4 r0 = r[0], r1 = r[1], r2 = r[2], r3 = r[3];

        u  = b0 * r0.x + b1 * r0.z + b2 * r1.x;
        v  = b0 * r0.y + b1 * r0.w + b2 * r1.y;
        nx = b0 * r1.z + b1 * r2.y + b2 * r3.x;
        ny = b0 * r1.w + b1 * r2.z + b2 * r3.y;
        nz = b0 * r2.x + b1 * r2.w + b2 * r3.z;
    }

    // ---- bilinear grid sample of interleaved albedo (zero padding) ----
    float x = (u + 1.0f) * (NU * 0.5f) - 0.5f;
    float y = (v + 1.0f) * (NU * 0.5f) - 0.5f;
    float x0f = floorf(x);
    float y0f = floorf(y);
    float wx = x - x0f;
    float wy = y - y0f;
    int x0 = (int)x0f;
    int y0 = (int)y0f;

    const float4* ab = aint + (size_t)b * NU * NU;
    float a0 = 0.f, a1 = 0.f, a2 = 0.f;

    #pragma unroll
    for (int corner = 0; corner < 4; ++corner) {
        int xi = x0 + (corner & 1);
        int yi = y0 + (corner >> 1);
        if (xi >= 0 && xi < NU && yi >= 0 && yi < NU) {
            float w = ((corner & 1) ? wx : (1.0f - wx)) *
                      ((corner >> 1) ? wy : (1.0f - wy));
            float4 t = ab[yi * NU + xi];
            a0 += w * t.x;
            a1 += w * t.y;
            a2 += w * t.z;
        }
    }

    // ---- SH shading ----
    float sh[9];
    sh[0] = 1.0f;
    sh[1] = nx;
    sh[2] = ny;
    sh[3] = nz;
    sh[4] = nx * ny;
    sh[5] = nx * nz;
    sh[6] = ny * nz;
    sh[7] = nx * nx - ny * ny;
    sh[8] = 3.0f * nz * nz - 1.0f;

    float s0 = 0.f, s1 = 0.f, s2 = 0.f;
    #pragma unroll
    for (int k = 0; k < 9; ++k) {
        s0 += Ls[k * 3 + 0] * sh[k];
        s1 += Ls[k * 3 + 1] * sh[k];
        s2 += Ls[k * 3 + 2] * sh[k];
    }

    const size_t hw = (size_t)NH * NW;
    out[((size_t)b * 3 + 0) * hw + p] = a0 * s0;
    out[((size_t)b * 3 + 1) * hw + p] = a1 * s1;
    out[((size_t)b * 3 + 2) * hw + p] = a2 * s2;
}

extern "C" void kernel_launch(void* const* d_in, const int* in_sizes, int n_in,
                              void* d_out, int out_size, void* d_ws, size_t ws_size,
                              hipStream_t stream) {
    const float* vertices = (const float*)d_in[0];
    // d_in[1] transformed_vertices: dead for the output
    const float* albedos  = (const float*)d_in[2];
    const float* lights   = (const float*)d_in[3];
    const float* uvc      = (const float*)d_in[4];
    const float* bary     = (const float*)d_in[5];
    const int*   faces    = (const int*)d_in[6];
    const int*   p2f      = (const int*)d_in[7];
    float*       out      = (float*)d_out;

    // workspace layout
    char* ws = (char*)d_ws;
    float* nrm = (float*)ws;                                   // B*V*3 = 241 KB
    size_t nrm_bytes = (size_t)NB * NV * 3 * sizeof(float);
    size_t off = (nrm_bytes + 255) & ~(size_t)255;
    float* recs = (float*)(ws + off);                          // B*F*16 fl = 2.55 MB
    off += (size_t)NB * NF * 16 * sizeof(float);
    off = (off + 255) & ~(size_t)255;
    float4* aint = (float4*)(ws + off);                        // B*U*U float4 = 4.2 MB

    {
        zero_nrm_kernel<<<(NRM_FLOATS + 255) / 256, 256, 0, stream>>>(nrm);
    }
    {
        int n = NB * NF;
        face_accum_kernel<<<(n + 255) / 256, 256, 0, stream>>>(vertices, faces, nrm);
    }
    {
        prep_kernel<<<FACE_BLOCKS + ALB_BLOCKS, 256, 0, stream>>>(
            nrm, faces, uvc, albedos, recs, aint);
    }
    {
        dim3 grid((NH * NW + 255) / 256, NB);
        render_kernel<<<grid, 256, 0, stream>>>((const float4*)recs, aint, lights,
                                                bary, p2f, out);
    }
}

// Round 5
// 62.503 us; speedup vs baseline: 1.0839x; 1.0839x over previous
//
#include <hip/hip_runtime.h>
#include <math.h>

#define NB 4
#define NV 5023
#define NF 9976
#define NH 512
#define NW 512
#define NU 256   // albedo resolution

// CONST_FACTOR
__device__ __constant__ float d_cf[9] = {
    0.28209479177387814f,
    1.0233267079464885f,
    1.0233267079464885f,
    1.0233267079464885f,
    0.8580855308091875f,
    0.8580855308091875f,
    0.8580855308091875f,
    0.42904276540459376f,
    0.24770795610037571f
};

#define NRM_FLOATS  (NB * NV * 3)            // 60276
#define ZERO_BLOCKS ((NRM_FLOATS + 255) / 256)
#define ALB_ITEMS   (NB * NU * NU)           // 262144
#define ALB_BLOCKS  (ALB_ITEMS / 256)        // 1024
#define FACE_ITEMS  (NB * NF)
#define FACE_BLOCKS ((FACE_ITEMS + 255) / 256)

// ---------------------------------------------------------------------------
// Kernel 1 (fused independent prep): zero nrm accumulator + interleave
// albedos (B,3,U,U) -> (B,U,U,4) float4. No cross dependence.
// ---------------------------------------------------------------------------
__global__ void init_kernel(float*       __restrict__ nrm,
                            const float* __restrict__ albedos,
                            float4*      __restrict__ aint) {
    if (blockIdx.x < ZERO_BLOCKS) {
        int i = blockIdx.x * blockDim.x + threadIdx.x;
        if (i < NRM_FLOATS) nrm[i] = 0.0f;
    } else {
        int j = (blockIdx.x - ZERO_BLOCKS) * blockDim.x + threadIdx.x;
        int b = j / (NU * NU);
        int o = j - b * (NU * NU);
        const float* ab = albedos + (size_t)b * 3 * NU * NU;
        aint[j] = make_float4(ab[o], ab[NU * NU + o], ab[2 * NU * NU + o], 0.0f);
    }
}

// ---------------------------------------------------------------------------
// Kernel 2: accumulate (unnormalized) vertex normals via atomics.
// ---------------------------------------------------------------------------
__global__ void face_accum_kernel(const float* __restrict__ verts,
                                  const int*   __restrict__ faces,
                                  float*       __restrict__ nrm) {
    int idx = blockIdx.x * blockDim.x + threadIdx.x;   // b*NF + f
    if (idx >= NB * NF) return;
    int b = idx / NF;
    int f = idx - b * NF;

    int i0 = faces[f * 3 + 0];
    int i1 = faces[f * 3 + 1];
    int i2 = faces[f * 3 + 2];

    const float* vb = verts + (size_t)b * NV * 3;
    float v0x = vb[i0 * 3 + 0], v0y = vb[i0 * 3 + 1], v0z = vb[i0 * 3 + 2];
    float v1x = vb[i1 * 3 + 0], v1y = vb[i1 * 3 + 1], v1z = vb[i1 * 3 + 2];
    float v2x = vb[i2 * 3 + 0], v2y = vb[i2 * 3 + 1], v2z = vb[i2 * 3 + 2];

    float ax = v1x - v0x, ay = v1y - v0y, az = v1z - v0z;
    float bx = v2x - v0x, by = v2y - v0y, bz = v2z - v0z;
    float cx = ay * bz - az * by;
    float cy = az * bx - ax * bz;
    float cz = ax * by - ay * bx;

    float* nb = nrm + (size_t)b * NV * 3;
    atomicAdd(&nb[i0 * 3 + 0], cx);
    atomicAdd(&nb[i0 * 3 + 1], cy);
    atomicAdd(&nb[i0 * 3 + 2], cz);
    atomicAdd(&nb[i1 * 3 + 0], cx);
    atomicAdd(&nb[i1 * 3 + 1], cy);
    atomicAdd(&nb[i1 * 3 + 2], cz);
    atomicAdd(&nb[i2 * 3 + 0], cx);
    atomicAdd(&nb[i2 * 3 + 1], cy);
    atomicAdd(&nb[i2 * 3 + 2], cz);
}

// ---------------------------------------------------------------------------
// Kernel 3: pack per-(b,f) 64B face records:
//   [u0,v0,u1,v1, u2,v2,n0x,n0y, n0z,n1x,n1y,n1z, n2x,n2y,n2z,pad]
// (normals normalized on the fly)
// ---------------------------------------------------------------------------
__global__ void pack_kernel(const float* __restrict__ nrm,
                            const int*   __restrict__ faces,
                            const float* __restrict__ uvc,      // (1,F,3,3)
                            float*       __restrict__ recs) {   // (B*F,16)
    int idx = blockIdx.x * blockDim.x + threadIdx.x;            // b*NF + f
    if (idx >= FACE_ITEMS) return;
    int b = idx / NF;
    int f = idx - b * NF;

    int i0 = faces[f * 3 + 0];
    int i1 = faces[f * 3 + 1];
    int i2 = faces[f * 3 + 2];

    const float* nb = nrm + (size_t)b * NV * 3;
    float n0x = nb[i0 * 3 + 0], n0y = nb[i0 * 3 + 1], n0z = nb[i0 * 3 + 2];
    float n1x = nb[i1 * 3 + 0], n1y = nb[i1 * 3 + 1], n1z = nb[i1 * 3 + 2];
    float n2x = nb[i2 * 3 + 0], n2y = nb[i2 * 3 + 1], n2z = nb[i2 * 3 + 2];

    float l0 = 1.0f / fmaxf(sqrtf(n0x*n0x + n0y*n0y + n0z*n0z), 1e-6f);
    float l1 = 1.0f / fmaxf(sqrtf(n1x*n1x + n1y*n1y + n1z*n1z), 1e-6f);
    float l2 = 1.0f / fmaxf(sqrtf(n2x*n2x + n2y*n2y + n2z*n2z), 1e-6f);

    const float* uvf = uvc + (size_t)f * 9;  // [vert][comp]

    float4* r = (float4*)(recs + (size_t)idx * 16);
    r[0] = make_float4(uvf[0], uvf[1], uvf[3], uvf[4]);          // u0 v0 u1 v1
    r[1] = make_float4(uvf[6], uvf[7], n0x * l0, n0y * l0);      // u2 v2 n0x n0y
    r[2] = make_float4(n0z * l0, n1x * l1, n1y * l1, n1z * l1);  // n0z n1
    r[3] = make_float4(n2x * l2, n2y * l2, n2z * l2, 0.0f);      // n2 pad
}

// ---------------------------------------------------------------------------
// Kernel 4: per-pixel render, XCD-pinned: block i runs on XCD (i&7)
// (x-fastest round-robin dispatch), batch b = (i&7)>>1 so each XCD's gather
// working set (aint 1.0MB + recs 0.64MB for ONE batch) is L2-resident.
// ---------------------------------------------------------------------------
__global__ void render_kernel(const float4* __restrict__ recs,   // (B*F,4 float4)
                              const float4* __restrict__ aint,   // (B,U,U)
                              const float* __restrict__ lights,
                              const float* __restrict__ bary,    // (B,H,W,1,3)
                              const int*   __restrict__ p2f,     // (B,H,W,1)
                              float*       __restrict__ out) {   // (B,3,H,W)
    const int blk = blockIdx.x;
    const int xcd = blk & 7;
    const int b   = xcd >> 1;                       // 2 XCDs per batch
    const int j   = ((blk >> 3) << 1) | (xcd & 1);  // 0..1023 within batch
    const int p   = j * 256 + threadIdx.x;          // h*W + w

    const int pix = b * NH * NW + p;
    // issue the dependent-chain head loads early
    const int f = p2f[pix];
    const float* bc = bary + (size_t)pix * 3;
    float b0 = bc[0], b1 = bc[1], b2 = bc[2];

    __shared__ float Ls[27];
    if (threadIdx.x < 27) {
        int k = threadIdx.x / 3;
        int c = threadIdx.x - k * 3;
        Ls[threadIdx.x] = lights[(b * 9 + k) * 3 + c] * d_cf[k];
    }
    __syncthreads();

    float u = 0.f, v = 0.f, nx = 0.f, ny = 0.f, nz = 0.f;
    if (f >= 0) {
        const float4* r = recs + ((size_t)b * NF + f) * 4;
        float4 r0 = r[0], r1 = r[1], r2 = r[2], r3 = r[3];

        u  = b0 * r0.x + b1 * r0.z + b2 * r1.x;
        v  = b0 * r0.y + b1 * r0.w + b2 * r1.y;
        nx = b0 * r1.z + b1 * r2.y + b2 * r3.x;
        ny = b0 * r1.w + b1 * r2.z + b2 * r3.y;
        nz = b0 * r2.x + b1 * r2.w + b2 * r3.z;
    }

    // ---- bilinear grid sample of interleaved albedo (zero padding) ----
    float x = (u + 1.0f) * (NU * 0.5f) - 0.5f;
    float y = (v + 1.0f) * (NU * 0.5f) - 0.5f;
    float x0f = floorf(x);
    float y0f = floorf(y);
    float wx = x - x0f;
    float wy = y - y0f;
    int x0 = (int)x0f;
    int y0 = (int)y0f;

    const float4* ab = aint + (size_t)b * NU * NU;
    float a0 = 0.f, a1 = 0.f, a2 = 0.f;

    #pragma unroll
    for (int corner = 0; corner < 4; ++corner) {
        int xi = x0 + (corner & 1);
        int yi = y0 + (corner >> 1);
        if (xi >= 0 && xi < NU && yi >= 0 && yi < NU) {
            float w = ((corner & 1) ? wx : (1.0f - wx)) *
                      ((corner >> 1) ? wy : (1.0f - wy));
            float4 t = ab[yi * NU + xi];
            a0 += w * t.x;
            a1 += w * t.y;
            a2 += w * t.z;
        }
    }

    // ---- SH shading ----
    float sh[9];
    sh[0] = 1.0f;
    sh[1] = nx;
    sh[2] = ny;
    sh[3] = nz;
    sh[4] = nx * ny;
    sh[5] = nx * nz;
    sh[6] = ny * nz;
    sh[7] = nx * nx - ny * ny;
    sh[8] = 3.0f * nz * nz - 1.0f;

    float s0 = 0.f, s1 = 0.f, s2 = 0.f;
    #pragma unroll
    for (int k = 0; k < 9; ++k) {
        s0 += Ls[k * 3 + 0] * sh[k];
        s1 += Ls[k * 3 + 1] * sh[k];
        s2 += Ls[k * 3 + 2] * sh[k];
    }

    const size_t hw = (size_t)NH * NW;
    out[((size_t)b * 3 + 0) * hw + p] = a0 * s0;
    out[((size_t)b * 3 + 1) * hw + p] = a1 * s1;
    out[((size_t)b * 3 + 2) * hw + p] = a2 * s2;
}

extern "C" void kernel_launch(void* const* d_in, const int* in_sizes, int n_in,
                              void* d_out, int out_size, void* d_ws, size_t ws_size,
                              hipStream_t stream) {
    const float* vertices = (const float*)d_in[0];
    // d_in[1] transformed_vertices: dead for the output
    const float* albedos  = (const float*)d_in[2];
    const float* lights   = (const float*)d_in[3];
    const float* uvc      = (const float*)d_in[4];
    const float* bary     = (const float*)d_in[5];
    const int*   faces    = (const int*)d_in[6];
    const int*   p2f      = (const int*)d_in[7];
    float*       out      = (float*)d_out;

    // workspace layout
    char* ws = (char*)d_ws;
    float* nrm = (float*)ws;                                   // B*V*3 = 241 KB
    size_t nrm_bytes = (size_t)NB * NV * 3 * sizeof(float);
    size_t off = (nrm_bytes + 255) & ~(size_t)255;
    float* recs = (float*)(ws + off);                          // B*F*16 fl = 2.55 MB
    off += (size_t)NB * NF * 16 * sizeof(float);
    off = (off + 255) & ~(size_t)255;
    float4* aint = (float4*)(ws + off);                        // B*U*U float4 = 4.2 MB

    {
        init_kernel<<<ZERO_BLOCKS + ALB_BLOCKS, 256, 0, stream>>>(nrm, albedos, aint);
    }
    {
        int n = NB * NF;
        face_accum_kernel<<<(n + 255) / 256, 256, 0, stream>>>(vertices, faces, nrm);
    }
    {
        pack_kernel<<<FACE_BLOCKS, 256, 0, stream>>>(nrm, faces, uvc, recs);
    }
    {
        render_kernel<<<NB * 1024, 256, 0, stream>>>((const float4*)recs, aint,
                                                     lights, bary, p2f, out);
    }
}